// Round 15
// baseline (102.129 us; speedup 1.0000x reference)
//
#include <hip/hip_runtime.h>
#include <hip/hip_bf16.h>

// Problem constants (from reference setup_inputs)
#define RR 3
#define BB 2
#define NN 2048
#define DD 128
#define HH 4
#define HD 32
#define LEAKY 0.2f
#define LN_EPS 1e-5f
#define LOG2E 1.4426950408889634f

using f32x4  = __attribute__((ext_vector_type(4))) float;
using bf16x8 = __attribute__((ext_vector_type(8))) short;

__device__ __forceinline__ void gload_lds16(const void* g, void* l) {
    __builtin_amdgcn_global_load_lds(
        (const __attribute__((address_space(1))) unsigned*)g,
        (__attribute__((address_space(3))) unsigned*)l, 16, 0, 0);
}
__device__ __forceinline__ void gload_lds4(const void* g, void* l) {
    __builtin_amdgcn_global_load_lds(
        (const __attribute__((address_space(1))) unsigned*)g,
        (__attribute__((address_space(3))) unsigned*)l, 4, 0, 0);
}
__device__ __forceinline__ unsigned short bfb(float x) {
    return __builtin_bit_cast(unsigned short, __float2bfloat16(x));
}

// ---------------------------------------------------------------------------
// DIAGNOSTIC ROUND: prep_kernel is launched 3x (idempotent — pure function
// of inputs, full overwrites). total = base + 2*prep  =>  prep = (total-65.5)/2.
// All kernels byte-identical to R14.
// ---------------------------------------------------------------------------

// ---------------------------------------------------------------------------
// Bitmask layout (ballot-native): per row (2048 j): 8 chunks of 256 j;
// per chunk 8 words [q][half]; word bit i <-> j = chunk*256 + half*128 + 4i + q.
// Consumer (gat): bit (c>>2) of (word[c&3] >> (jc*8 + kg*2)).
// ---------------------------------------------------------------------------
__global__ __launch_bounds__(256) void prep_kernel(
    const float* __restrict__ H, const int* __restrict__ A,
    const float* __restrict__ W,
    const float* __restrict__ a_src, const float* __restrict__ a_dst,
    float* __restrict__ es, float* __restrict__ ed,
    __hip_bfloat16* __restrict__ whT, unsigned* __restrict__ bm)
{
    const int bid = blockIdx.x;
    const int t = threadIdx.x;

    if (bid >= 384) {
        // ---- ballot compact role: wave handles one A row (2048 ints) ----
        const int cb = bid - 384;                       // 0..3071
        const long crow = (long)cb * 4 + (t >> 6);      // A row 0..12287
        const int lane = t & 63;
        const int4* Ap = (const int4*)A + crow * 512 + lane;

        // phase 1: issue ALL 8 loads (8KB in flight per wave)
        int4 v[8];
#pragma unroll
        for (int e = 0; e < 8; ++e) v[e] = Ap[e * 64];

        // phase 2: ballots; lane l captures word (e,q,half)=(l>>3,(l>>1)&3,l&1)
        const int sel_e = lane >> 3;
        const int sel_q = (lane >> 1) & 3;
        const int sel_h = lane & 1;
        unsigned word = 0;
#pragma unroll
        for (int e = 0; e < 8; ++e) {
            const unsigned long long B0 = __ballot(v[e].x != 0);
            const unsigned long long B1 = __ballot(v[e].y != 0);
            const unsigned long long B2 = __ballot(v[e].z != 0);
            const unsigned long long B3 = __ballot(v[e].w != 0);
            if (sel_e == e) {
                const unsigned long long Bq =
                    (sel_q == 3) ? B3 : (sel_q == 2) ? B2 : (sel_q == 1) ? B1 : B0;
                word = sel_h ? (unsigned)(Bq >> 32) : (unsigned)Bq;
            }
        }
        // one coalesced 256B store per wave-row
        bm[crow * 64 + lane] = word;
        return;
    }

    // ---- wh role ----
    const int rbh = bid >> 4;          // (r*BB+b)*HH+h
    const int nch = bid & 15;          // 128-col chunk
    const int h = rbh & 3;
    const int b = (rbh >> 2) & 1;
    const int r = rbh >> 3;
    const int wi = r * HH + h;
    const int w  = t >> 6;
    const int l  = t & 63;
    const int lr = l & 15;
    const int lg = l >> 4;

    const float* Wp = W + (long)wi * DD * HD;
    bf16x8 afr[2][4];
#pragma unroll
    for (int mt = 0; mt < 2; ++mt)
#pragma unroll
        for (int kt = 0; kt < 4; ++kt)
#pragma unroll
            for (int e = 0; e < 8; ++e)
                afr[mt][kt][e] = (short)bfb(Wp[(kt * 32 + lg * 8 + e) * HD + mt * 16 + lr]);

    float av[2][4], dv[2][4];
#pragma unroll
    for (int mt = 0; mt < 2; ++mt)
#pragma unroll
        for (int reg = 0; reg < 4; ++reg) {
            const int f = mt * 16 + lg * 4 + reg;
            av[mt][reg] = a_src[wi * HD + f] * LOG2E;
            dv[mt][reg] = a_dst[wi * HD + f] * LOG2E;
        }

#pragma unroll
    for (int nt = 0; nt < 2; ++nt) {
        const int ncol = nch * 128 + w * 32 + nt * 16 + lr;
        const float4* hrow4 = (const float4*)(H + ((long)b * NN + ncol) * DD);
        f32x4 acc0 = {0.f, 0.f, 0.f, 0.f};
        f32x4 acc1 = {0.f, 0.f, 0.f, 0.f};
#pragma unroll
        for (int kt = 0; kt < 4; ++kt) {
            float4 h0 = hrow4[kt * 8 + lg * 2];
            float4 h1 = hrow4[kt * 8 + lg * 2 + 1];
            bf16x8 bfr;
            bfr[0] = (short)bfb(h0.x); bfr[1] = (short)bfb(h0.y);
            bfr[2] = (short)bfb(h0.z); bfr[3] = (short)bfb(h0.w);
            bfr[4] = (short)bfb(h1.x); bfr[5] = (short)bfb(h1.y);
            bfr[6] = (short)bfb(h1.z); bfr[7] = (short)bfb(h1.w);
            acc0 = __builtin_amdgcn_mfma_f32_16x16x32_bf16(afr[0][kt], bfr, acc0, 0, 0, 0);
            acc1 = __builtin_amdgcn_mfma_f32_16x16x32_bf16(afr[1][kt], bfr, acc1, 0, 0, 0);
        }
        float s = 0.f, d = 0.f;
#pragma unroll
        for (int reg = 0; reg < 4; ++reg) {
            const int f0 = lg * 4 + reg;
            const int f1 = 16 + lg * 4 + reg;
            whT[((long)rbh * HD + f0) * NN + ncol] = __float2bfloat16(acc0[reg]);
            whT[((long)rbh * HD + f1) * NN + ncol] = __float2bfloat16(acc1[reg]);
            s = fmaf(acc0[reg], av[0][reg], s);
            s = fmaf(acc1[reg], av[1][reg], s);
            d = fmaf(acc0[reg], dv[0][reg], d);
            d = fmaf(acc1[reg], dv[1][reg], d);
        }
        s += __shfl_xor(s, 16); s += __shfl_xor(s, 32);
        d += __shfl_xor(d, 16); d += __shfl_xor(d, 32);
        if (l < 16) {
            es[(long)rbh * NN + ncol] = s;
            ed[(long)rbh * NN + ncol] = d;
        }
    }
}

// ---------------------------------------------------------------------------
// Kernel 2: fused masked softmax + MFMA aggregation (R13/R14 structure).
// ---------------------------------------------------------------------------
__global__ __launch_bounds__(256, 3) void gat_attn_kernel(
    const unsigned* __restrict__ bm, const float* __restrict__ es,
    const float* __restrict__ ed, const __hip_bfloat16* __restrict__ whT,
    unsigned* __restrict__ num, float* __restrict__ den)
{
    const int lg = ((int)blockIdx.x % 8) * 96 + (int)blockIdx.x / 8;
    const int jh = lg & 1;
    const int it = (lg >> 1) & 15;
    const int h  = (lg >> 5) & 3;
    const int b  = (lg >> 7) & 1;
    const int r  = lg >> 8;
    const int i0 = it << 7;
    const int tid = threadIdx.x;
    const int w = tid >> 6;
    const int l = tid & 63;
    const int row = l & 15;
    const int kg  = l >> 4;
    const int f31 = l & 31;
    const int kgr = l >> 5;

    __shared__ __align__(16) short    whs[2][4][4][32][8];
    __shared__ __align__(16) unsigned bms[2][4][128];
    __shared__ __align__(16) float    eds[2][4][32];
    __shared__ float red[4];

    const int rbh = (r * BB + b) * HH + h;
    const long rbNN = (long)(r * BB + b) * NN;
    const __hip_bfloat16* whTr = whT + (long)rbh * HD * NN;
    const float* edr = ed + (long)rbh * NN;
    const int jbase = jh * (NN / 2);

#define STAGE(s, nb) do {                                                           \
        const int j0s = jbase + (s) * 128;                                          \
        const int S_ = jh * 8 + (s);                                                \
        const int woff_ = (S_ >> 1) * 8 + (S_ & 1) + w * 2;                         \
        gload_lds16(whTr + (long)f31 * NN + j0s + w * 32 + kgr * 8,                 \
                    &whs[nb][w][0][0][0]);                                          \
        gload_lds16(whTr + (long)f31 * NN + j0s + w * 32 + (2 + kgr) * 8,           \
                    &whs[nb][w][2][0][0]);                                          \
        gload_lds4(bm + (rbNN + i0 + l) * 64 + woff_, &bms[nb][w][0]);              \
        gload_lds4(bm + (rbNN + i0 + 64 + l) * 64 + woff_, &bms[nb][w][64]);        \
        if (l < 32) gload_lds4(edr + j0s + w * 32 + l, &eds[nb][w][0]);             \
    } while (0)

    STAGE(0, 0);

    // block-wide max of ed (upper bound; cancels exactly in num/den)
    float4 m0 = ((const float4*)edr)[tid * 2];
    float4 m1 = ((const float4*)edr)[tid * 2 + 1];
    float mm = fmaxf(fmaxf(fmaxf(m0.x, m0.y), fmaxf(m0.z, m0.w)),
                     fmaxf(fmaxf(m1.x, m1.y), fmaxf(m1.z, m1.w)));
#pragma unroll
    for (int d = 1; d < 64; d <<= 1) mm = fmaxf(mm, __shfl_xor(mm, d));
    if (l == 0) red[w] = mm;
    __syncthreads();
    const float medf = fmaxf(fmaxf(red[0], red[1]), fmaxf(red[2], red[3]));

    const float esvA = es[(long)rbh * NN + i0 + w * 16 + row];
    const float esvB = es[(long)rbh * NN + i0 + 64 + w * 16 + row];
    const float xA = esvA + medf, xB = esvB + medf;
    const float MA = fmaxf(xA, LEAKY * xA), MB = fmaxf(xB, LEAKY * xB);
    const float uA = esvA - MA, vA = fmaf(LEAKY, esvA, -MA);
    const float uB = esvB - MB, vB = fmaf(LEAKY, esvB, -MB);

    f32x4 acc0A = {0,0,0,0}, acc1A = {0,0,0,0}, accDA = {0,0,0,0};
    f32x4 acc0B = {0,0,0,0}, acc1B = {0,0,0,0}, accDB = {0,0,0,0};
    bf16x8 ones;
#pragma unroll
    for (int i = 0; i < 8; ++i) ones[i] = (short)0x3F80;

    const int kk = kg * 2;
    const int rAi = w * 16 + row, rBi = 64 + w * 16 + row;

    for (int s = 0; s < 8; ++s) {
        const int cb = s & 1, nb = cb ^ 1;
        if (s < 7) {
            STAGE(s + 1, nb);
            asm volatile("s_waitcnt vmcnt(5)" ::: "memory");
        } else {
            asm volatile("s_waitcnt vmcnt(0)" ::: "memory");
        }
        __builtin_amdgcn_s_barrier();
        __builtin_amdgcn_sched_barrier(0);

        unsigned wA[4], wB[4];
#pragma unroll
        for (int q = 0; q < 4; ++q) {
            wA[q] = bms[cb][q][rAi];
            wB[q] = bms[cb][q][rBi];
        }

#pragma unroll
        for (int jc = 0; jc < 4; ++jc) {
            bf16x8 b0 = *(const bf16x8*)&whs[cb][jc][kg][row][0];
            bf16x8 b1 = *(const bf16x8*)&whs[cb][jc][kg][row + 16][0];
            float4 e0 = *(const float4*)&eds[cb][jc][kg * 8];
            float4 e1 = *(const float4*)&eds[cb][jc][kg * 8 + 4];

            unsigned uAq[4], uBq[4];
#pragma unroll
            for (int q = 0; q < 4; ++q) {
                uAq[q] = wA[q] >> (jc * 8 + kk);
                uBq[q] = wB[q] >> (jc * 8 + kk);
            }

            float ev[8];
            ev[0] = e0.x; ev[1] = e0.y; ev[2] = e0.z; ev[3] = e0.w;
            ev[4] = e1.x; ev[5] = e1.y; ev[6] = e1.z; ev[7] = e1.w;

            bf16x8 pA, pB;
#pragma unroll
            for (int c = 0; c < 8; ++c) {
                float pa = __builtin_amdgcn_exp2f(
                    fmaxf(uA + ev[c], fmaf(LEAKY, ev[c], vA)));
                float pb = __builtin_amdgcn_exp2f(
                    fmaxf(uB + ev[c], fmaf(LEAKY, ev[c], vB)));
                const int ma = ((int)(uAq[c & 3] << (31 - (c >> 2)))) >> 31;
                const int mb = ((int)(uBq[c & 3] << (31 - (c >> 2)))) >> 31;
                pa = __uint_as_float(__float_as_uint(pa) & (unsigned)ma);
                pb = __uint_as_float(__float_as_uint(pb) & (unsigned)mb);
                __hip_bfloat16 ha = __float2bfloat16(pa);
                __hip_bfloat16 hb = __float2bfloat16(pb);
                pA[c] = __builtin_bit_cast(short, ha);
                pB[c] = __builtin_bit_cast(short, hb);
            }

            __builtin_amdgcn_s_setprio(1);
            acc0A = __builtin_amdgcn_mfma_f32_16x16x32_bf16(pA, b0, acc0A, 0, 0, 0);
            acc1A = __builtin_amdgcn_mfma_f32_16x16x32_bf16(pA, b1, acc1A, 0, 0, 0);
            accDA = __builtin_amdgcn_mfma_f32_16x16x32_bf16(pA, ones, accDA, 0, 0, 0);
            acc0B = __builtin_amdgcn_mfma_f32_16x16x32_bf16(pB, b0, acc0B, 0, 0, 0);
            acc1B = __builtin_amdgcn_mfma_f32_16x16x32_bf16(pB, b1, acc1B, 0, 0, 0);
            accDB = __builtin_amdgcn_mfma_f32_16x16x32_bf16(pB, ones, accDB, 0, 0, 0);
            __builtin_amdgcn_s_setprio(0);
        }
        __builtin_amdgcn_s_barrier();
        __builtin_amdgcn_sched_barrier(0);
    }
#undef STAGE

    const int fcol = l & 15;
    const int pr = r * 2 + jh;
#pragma unroll
    for (int reg = 0; reg < 4; ++reg) {
        const int orow = (l >> 4) * 4 + reg;
        const long roA = (long)pr * (BB * NN) + (long)b * NN + i0 + w * 16 + orow;
        const long roB = roA + 64;
        const unsigned wa = (unsigned)bfb(acc0A[reg]) | ((unsigned)bfb(acc1A[reg]) << 16);
        const unsigned wb_ = (unsigned)bfb(acc0B[reg]) | ((unsigned)bfb(acc1B[reg]) << 16);
        num[roA * 64 + h * 16 + fcol] = wa;
        num[roB * 64 + h * 16 + fcol] = wb_;
        if (fcol == 0) {
            den[roA * HH + h] = accDA[reg];
            den[roB * HH + h] = accDB[reg];
        }
    }
}

// ---------------------------------------------------------------------------
// Kernel 3: out = LayerNorm(H + mean_r (num_r / den_r)).
// ---------------------------------------------------------------------------
__global__ __launch_bounds__(256) void finalize_kernel(
    const float* __restrict__ H, const unsigned* __restrict__ num,
    const float* __restrict__ den,
    const float* __restrict__ gamma, const float* __restrict__ beta,
    float* __restrict__ out)
{
    const int w = threadIdx.x >> 6;
    const int l = threadIdx.x & 63;
    const long row = (long)blockIdx.x * 4 + w;
    const int hh = l >> 4, cc = l & 15;
    const int c_lo = hh * 32 + cc, c_hi = c_lo + 16;
    const float hx = H[row * DD + c_lo];
    const float hy = H[row * DD + c_hi];

    float ax = 0.f, ay = 0.f;
#pragma unroll
    for (int r = 0; r < RR; ++r) {
        float dsum = 0.f, nx = 0.f, ny = 0.f;
#pragma unroll
        for (int j = 0; j < 2; ++j) {
            const long ro = (long)(r * 2 + j) * (BB * NN) + row;
            dsum += den[ro * HH + hh];
            const unsigned wv = num[ro * 64 + l];
            nx += __uint_as_float(wv << 16);
            ny += __uint_as_float(wv & 0xffff0000u);
        }
        const float inv = (dsum > 0.f) ? 1.0f / dsum : 0.0f;
        ax = fmaf(nx, inv, ax);
        ay = fmaf(ny, inv, ay);
    }
    const float x0 = hx + ax * (1.0f / RR);
    const float x1 = hy + ay * (1.0f / RR);
    float s = x0 + x1, q = x0 * x0 + x1 * x1;
#pragma unroll
    for (int m = 1; m < 64; m <<= 1) {
        s += __shfl_xor(s, m);
        q += __shfl_xor(q, m);
    }
    const float mu  = s * (1.0f / DD);
    const float var = q * (1.0f / DD) - mu * mu;
    const float inv = rsqrtf(var + LN_EPS);
    out[row * DD + c_lo] = (x0 - mu) * inv * gamma[c_lo] + beta[c_lo];
    out[row * DD + c_hi] = (x1 - mu) * inv * gamma[c_hi] + beta[c_hi];
}

// ---------------------------------------------------------------------------
extern "C" void kernel_launch(void* const* d_in, const int* in_sizes, int n_in,
                              void* d_out, int out_size, void* d_ws, size_t ws_size,
                              hipStream_t stream)
{
    const float* H      = (const float*)d_in[0];
    const int*   A      = (const int*)d_in[1];
    const float* W      = (const float*)d_in[2];
    const float* a_src  = (const float*)d_in[3];
    const float* a_dst  = (const float*)d_in[4];
    const float* gamma  = (const float*)d_in[5];
    const float* beta   = (const float*)d_in[6];
    float* out = (float*)d_out;

    // workspace carve (~13.4 MB)
    char* ws = (char*)d_ws;
    unsigned* num = (unsigned*)ws;               ws += (size_t)RR * 2 * BB * NN * 64 * 4;
    float* den = (float*)ws;                     ws += (size_t)RR * 2 * BB * NN * HH * 4;
    float* es  = (float*)ws;                     ws += (size_t)RR * BB * HH * NN * 4;
    float* ed  = (float*)ws;                     ws += (size_t)RR * BB * HH * NN * 4;
    __hip_bfloat16* whT = (__hip_bfloat16*)ws;   ws += (size_t)RR * BB * HH * HD * NN * 2;
    unsigned* bmask = (unsigned*)ws;             ws += (size_t)RR * BB * NN * (NN / 32) * 4;

    // DIAGNOSTIC: prep launched 3x (idempotent). prep_us = (total - 65.5)/2.
    prep_kernel<<<384 + RR * BB * NN * (NN / 32) / 256, 256, 0, stream>>>(
        H, A, W, a_src, a_dst, es, ed, whT, bmask);
    prep_kernel<<<384 + RR * BB * NN * (NN / 32) / 256, 256, 0, stream>>>(
        H, A, W, a_src, a_dst, es, ed, whT, bmask);
    prep_kernel<<<384 + RR * BB * NN * (NN / 32) / 256, 256, 0, stream>>>(
        H, A, W, a_src, a_dst, es, ed, whT, bmask);
    gat_attn_kernel<<<RR * BB * HH * 16 * 2, 256, 0, stream>>>(bmask, es, ed, whT, num, den);
    finalize_kernel<<<BB * NN / 4, 256, 0, stream>>>(H, num, den, gamma, beta, out);
}

// Round 18
// 72.696 us; speedup vs baseline: 1.4049x; 1.4049x over previous
//
#include <hip/hip_runtime.h>
#include <hip/hip_bf16.h>

// Problem constants (from reference setup_inputs)
#define RR 3
#define BB 2
#define NN 2048
#define DD 128
#define HH 4
#define HD 32
#define LEAKY 0.2f
#define LN_EPS 1e-5f
#define LOG2E 1.4426950408889634f

using f32x4  = __attribute__((ext_vector_type(4))) float;
using bf16x8 = __attribute__((ext_vector_type(8))) short;

__device__ __forceinline__ void gload_lds16(const void* g, void* l) {
    __builtin_amdgcn_global_load_lds(
        (const __attribute__((address_space(1))) unsigned*)g,
        (__attribute__((address_space(3))) unsigned*)l, 16, 0, 0);
}
__device__ __forceinline__ void gload_lds4(const void* g, void* l) {
    __builtin_amdgcn_global_load_lds(
        (const __attribute__((address_space(1))) unsigned*)g,
        (__attribute__((address_space(3))) unsigned*)l, 4, 0, 0);
}
__device__ __forceinline__ unsigned short bfb(float x) {
    return __builtin_bit_cast(unsigned short, __float2bfloat16(x));
}

// ---------------------------------------------------------------------------
// Bitmask layout (ballot-native): per row (2048 j): 8 chunks of 256 j;
// per chunk 8 words [q][half]; word bit i <-> j = chunk*256 + half*128 + 4i + q.
// Consumer (gat): bit (c>>2) of (word[c&3] >> (jc*8 + kg*2)).
// ---------------------------------------------------------------------------
__global__ __launch_bounds__(256) void prep_kernel(
    const float* __restrict__ H, const int* __restrict__ A,
    const float* __restrict__ W,
    const float* __restrict__ a_src, const float* __restrict__ a_dst,
    float* __restrict__ es, float* __restrict__ ed,
    __hip_bfloat16* __restrict__ whT, unsigned* __restrict__ bm)
{
    const int bid = blockIdx.x;
    const int t = threadIdx.x;

    if (bid >= 384) {
        // ---- ballot compact role: wave handles one A row (2048 ints) ----
        const int cb = bid - 384;                       // 0..3071
        const long crow = (long)cb * 4 + (t >> 6);      // A row 0..12287
        const int lane = t & 63;
        const int4* Ap = (const int4*)A + crow * 512 + lane;

        int4 v[8];
#pragma unroll
        for (int e = 0; e < 8; ++e) v[e] = Ap[e * 64];

        const int sel_e = lane >> 3;
        const int sel_q = (lane >> 1) & 3;
        const int sel_h = lane & 1;
        unsigned word = 0;
#pragma unroll
        for (int e = 0; e < 8; ++e) {
            const unsigned long long B0 = __ballot(v[e].x != 0);
            const unsigned long long B1 = __ballot(v[e].y != 0);
            const unsigned long long B2 = __ballot(v[e].z != 0);
            const unsigned long long B3 = __ballot(v[e].w != 0);
            if (sel_e == e) {
                const unsigned long long Bq =
                    (sel_q == 3) ? B3 : (sel_q == 2) ? B2 : (sel_q == 1) ? B1 : B0;
                word = sel_h ? (unsigned)(Bq >> 32) : (unsigned)Bq;
            }
        }
        bm[crow * 64 + lane] = word;
        return;
    }

    // ---- wh role ----
    const int rbh = bid >> 4;          // (r*BB+b)*HH+h
    const int nch = bid & 15;          // 128-col chunk
    const int h = rbh & 3;
    const int b = (rbh >> 2) & 1;
    const int r = rbh >> 3;
    const int wi = r * HH + h;
    const int w  = t >> 6;
    const int l  = t & 63;
    const int lr = l & 15;
    const int lg = l >> 4;

    const float* Wp = W + (long)wi * DD * HD;
    bf16x8 afr[2][4];
#pragma unroll
    for (int mt = 0; mt < 2; ++mt)
#pragma unroll
        for (int kt = 0; kt < 4; ++kt)
#pragma unroll
            for (int e = 0; e < 8; ++e)
                afr[mt][kt][e] = (short)bfb(Wp[(kt * 32 + lg * 8 + e) * HD + mt * 16 + lr]);

    float av[2][4], dv[2][4];
#pragma unroll
    for (int mt = 0; mt < 2; ++mt)
#pragma unroll
        for (int reg = 0; reg < 4; ++reg) {
            const int f = mt * 16 + lg * 4 + reg;
            av[mt][reg] = a_src[wi * HD + f] * LOG2E;
            dv[mt][reg] = a_dst[wi * HD + f] * LOG2E;
        }

#pragma unroll
    for (int nt = 0; nt < 2; ++nt) {
        const int ncol = nch * 128 + w * 32 + nt * 16 + lr;
        const float4* hrow4 = (const float4*)(H + ((long)b * NN + ncol) * DD);
        f32x4 acc0 = {0.f, 0.f, 0.f, 0.f};
        f32x4 acc1 = {0.f, 0.f, 0.f, 0.f};
#pragma unroll
        for (int kt = 0; kt < 4; ++kt) {
            float4 h0 = hrow4[kt * 8 + lg * 2];
            float4 h1 = hrow4[kt * 8 + lg * 2 + 1];
            bf16x8 bfr;
            bfr[0] = (short)bfb(h0.x); bfr[1] = (short)bfb(h0.y);
            bfr[2] = (short)bfb(h0.z); bfr[3] = (short)bfb(h0.w);
            bfr[4] = (short)bfb(h1.x); bfr[5] = (short)bfb(h1.y);
            bfr[6] = (short)bfb(h1.z); bfr[7] = (short)bfb(h1.w);
            acc0 = __builtin_amdgcn_mfma_f32_16x16x32_bf16(afr[0][kt], bfr, acc0, 0, 0, 0);
            acc1 = __builtin_amdgcn_mfma_f32_16x16x32_bf16(afr[1][kt], bfr, acc1, 0, 0, 0);
        }
        float s = 0.f, d = 0.f;
#pragma unroll
        for (int reg = 0; reg < 4; ++reg) {
            const int f0 = lg * 4 + reg;
            const int f1 = 16 + lg * 4 + reg;
            whT[((long)rbh * HD + f0) * NN + ncol] = __float2bfloat16(acc0[reg]);
            whT[((long)rbh * HD + f1) * NN + ncol] = __float2bfloat16(acc1[reg]);
            s = fmaf(acc0[reg], av[0][reg], s);
            s = fmaf(acc1[reg], av[1][reg], s);
            d = fmaf(acc0[reg], dv[0][reg], d);
            d = fmaf(acc1[reg], dv[1][reg], d);
        }
        s += __shfl_xor(s, 16); s += __shfl_xor(s, 32);
        d += __shfl_xor(d, 16); d += __shfl_xor(d, 32);
        if (l < 16) {
            es[(long)rbh * NN + ncol] = s;
            ed[(long)rbh * NN + ncol] = d;
        }
    }
}

// ---------------------------------------------------------------------------
// Kernel 2: fused masked softmax + MFMA aggregation. JS=4 j-split: each
// block covers 512 j (4 stages of 128) -> 1536 blocks = 6 blocks/CU = 75%
// occupancy. 6 barrier-desynchronized blocks per CU fill each other's
// stall bubbles (R15 diagnostic: gat was 40us at 3 blocks/CU, VALU ~33%).
// ---------------------------------------------------------------------------
__global__ __launch_bounds__(256, 6) void gat_attn_kernel(
    const unsigned* __restrict__ bm, const float* __restrict__ es,
    const float* __restrict__ ed, const __hip_bfloat16* __restrict__ whT,
    unsigned* __restrict__ num, float* __restrict__ den)
{
    // XCD-chunked bijective swizzle (1536 % 8 == 0)
    const int lg = ((int)blockIdx.x % 8) * 192 + (int)blockIdx.x / 8;
    const int jq = lg & 3;                 // j-quarter (512 j)
    const int it = (lg >> 2) & 15;
    const int h  = (lg >> 6) & 3;
    const int b  = (lg >> 8) & 1;
    const int r  = lg >> 9;
    const int i0 = it << 7;
    const int tid = threadIdx.x;
    const int w = tid >> 6;
    const int l = tid & 63;
    const int row = l & 15;
    const int kg  = l >> 4;
    const int f31 = l & 31;
    const int kgr = l >> 5;

    __shared__ __align__(16) short    whs[2][4][4][32][8];
    __shared__ __align__(16) unsigned bms[2][4][128];
    __shared__ __align__(16) float    eds[2][4][32];
    __shared__ float red[4];

    const int rbh = (r * BB + b) * HH + h;
    const long rbNN = (long)(r * BB + b) * NN;
    const __hip_bfloat16* whTr = whT + (long)rbh * HD * NN;
    const float* edr = ed + (long)rbh * NN;
    const int jbase = jq * (NN / 4);

#define STAGE(s, nb) do {                                                           \
        const int j0s = jbase + (s) * 128;                                          \
        const int S_ = jq * 4 + (s);                                                \
        const int woff_ = (S_ >> 1) * 8 + (S_ & 1) + w * 2;                         \
        gload_lds16(whTr + (long)f31 * NN + j0s + w * 32 + kgr * 8,                 \
                    &whs[nb][w][0][0][0]);                                          \
        gload_lds16(whTr + (long)f31 * NN + j0s + w * 32 + (2 + kgr) * 8,           \
                    &whs[nb][w][2][0][0]);                                          \
        gload_lds4(bm + (rbNN + i0 + l) * 64 + woff_, &bms[nb][w][0]);              \
        gload_lds4(bm + (rbNN + i0 + 64 + l) * 64 + woff_, &bms[nb][w][64]);        \
        if (l < 32) gload_lds4(edr + j0s + w * 32 + l, &eds[nb][w][0]);             \
    } while (0)

    STAGE(0, 0);

    // block-wide max of ed over ALL 2048 j (upper bound; cancels in num/den,
    // and identical across j-quarters so the final division is consistent)
    float4 m0 = ((const float4*)edr)[tid * 2];
    float4 m1 = ((const float4*)edr)[tid * 2 + 1];
    float mm = fmaxf(fmaxf(fmaxf(m0.x, m0.y), fmaxf(m0.z, m0.w)),
                     fmaxf(fmaxf(m1.x, m1.y), fmaxf(m1.z, m1.w)));
#pragma unroll
    for (int d = 1; d < 64; d <<= 1) mm = fmaxf(mm, __shfl_xor(mm, d));
    if (l == 0) red[w] = mm;
    __syncthreads();
    const float medf = fmaxf(fmaxf(red[0], red[1]), fmaxf(red[2], red[3]));

    const float esvA = es[(long)rbh * NN + i0 + w * 16 + row];
    const float esvB = es[(long)rbh * NN + i0 + 64 + w * 16 + row];
    const float xA = esvA + medf, xB = esvB + medf;
    const float MA = fmaxf(xA, LEAKY * xA), MB = fmaxf(xB, LEAKY * xB);
    const float uA = esvA - MA, vA = fmaf(LEAKY, esvA, -MA);
    const float uB = esvB - MB, vB = fmaf(LEAKY, esvB, -MB);

    f32x4 acc0A = {0,0,0,0}, acc1A = {0,0,0,0}, accDA = {0,0,0,0};
    f32x4 acc0B = {0,0,0,0}, acc1B = {0,0,0,0}, accDB = {0,0,0,0};
    bf16x8 ones;
#pragma unroll
    for (int i = 0; i < 8; ++i) ones[i] = (short)0x3F80;

    const int kk = kg * 2;
    const int rAi = w * 16 + row, rBi = 64 + w * 16 + row;

    for (int s = 0; s < 4; ++s) {
        const int cb = s & 1, nb = cb ^ 1;
        if (s < 3) {
            STAGE(s + 1, nb);
            asm volatile("s_waitcnt vmcnt(5)" ::: "memory");
        } else {
            asm volatile("s_waitcnt vmcnt(0)" ::: "memory");
        }
        __builtin_amdgcn_s_barrier();
        __builtin_amdgcn_sched_barrier(0);

        unsigned wA[4], wB[4];
#pragma unroll
        for (int q = 0; q < 4; ++q) {
            wA[q] = bms[cb][q][rAi];
            wB[q] = bms[cb][q][rBi];
        }

#pragma unroll
        for (int jc = 0; jc < 4; ++jc) {
            bf16x8 b0 = *(const bf16x8*)&whs[cb][jc][kg][row][0];
            bf16x8 b1 = *(const bf16x8*)&whs[cb][jc][kg][row + 16][0];
            float4 e0 = *(const float4*)&eds[cb][jc][kg * 8];
            float4 e1 = *(const float4*)&eds[cb][jc][kg * 8 + 4];

            unsigned uAq[4], uBq[4];
#pragma unroll
            for (int q = 0; q < 4; ++q) {
                uAq[q] = wA[q] >> (jc * 8 + kk);
                uBq[q] = wB[q] >> (jc * 8 + kk);
            }

            float ev[8];
            ev[0] = e0.x; ev[1] = e0.y; ev[2] = e0.z; ev[3] = e0.w;
            ev[4] = e1.x; ev[5] = e1.y; ev[6] = e1.z; ev[7] = e1.w;

            bf16x8 pA, pB;
#pragma unroll
            for (int c = 0; c < 8; ++c) {
                float pa = __builtin_amdgcn_exp2f(
                    fmaxf(uA + ev[c], fmaf(LEAKY, ev[c], vA)));
                float pb = __builtin_amdgcn_exp2f(
                    fmaxf(uB + ev[c], fmaf(LEAKY, ev[c], vB)));
                const int ma = ((int)(uAq[c & 3] << (31 - (c >> 2)))) >> 31;
                const int mb = ((int)(uBq[c & 3] << (31 - (c >> 2)))) >> 31;
                pa = __uint_as_float(__float_as_uint(pa) & (unsigned)ma);
                pb = __uint_as_float(__float_as_uint(pb) & (unsigned)mb);
                __hip_bfloat16 ha = __float2bfloat16(pa);
                __hip_bfloat16 hb = __float2bfloat16(pb);
                pA[c] = __builtin_bit_cast(short, ha);
                pB[c] = __builtin_bit_cast(short, hb);
            }

            __builtin_amdgcn_s_setprio(1);
            acc0A = __builtin_amdgcn_mfma_f32_16x16x32_bf16(pA, b0, acc0A, 0, 0, 0);
            acc1A = __builtin_amdgcn_mfma_f32_16x16x32_bf16(pA, b1, acc1A, 0, 0, 0);
            accDA = __builtin_amdgcn_mfma_f32_16x16x32_bf16(pA, ones, accDA, 0, 0, 0);
            acc0B = __builtin_amdgcn_mfma_f32_16x16x32_bf16(pB, b0, acc0B, 0, 0, 0);
            acc1B = __builtin_amdgcn_mfma_f32_16x16x32_bf16(pB, b1, acc1B, 0, 0, 0);
            accDB = __builtin_amdgcn_mfma_f32_16x16x32_bf16(pB, ones, accDB, 0, 0, 0);
            __builtin_amdgcn_s_setprio(0);
        }
        __builtin_amdgcn_s_barrier();
        __builtin_amdgcn_sched_barrier(0);
    }
#undef STAGE

    const int fcol = l & 15;
    const int pr = r * 4 + jq;
#pragma unroll
    for (int reg = 0; reg < 4; ++reg) {
        const int orow = (l >> 4) * 4 + reg;
        const long roA = (long)pr * (BB * NN) + (long)b * NN + i0 + w * 16 + orow;
        const long roB = roA + 64;
        const unsigned wa = (unsigned)bfb(acc0A[reg]) | ((unsigned)bfb(acc1A[reg]) << 16);
        const unsigned wb_ = (unsigned)bfb(acc0B[reg]) | ((unsigned)bfb(acc1B[reg]) << 16);
        num[roA * 64 + h * 16 + fcol] = wa;
        num[roB * 64 + h * 16 + fcol] = wb_;
        if (fcol == 0) {
            den[roA * HH + h] = accDA[reg];
            den[roB * HH + h] = accDB[reg];
        }
    }
}

// ---------------------------------------------------------------------------
// Kernel 3: out = LayerNorm(H + mean_r (num_r / den_r)); 4 j-chunks now.
// ---------------------------------------------------------------------------
__global__ __launch_bounds__(256) void finalize_kernel(
    const float* __restrict__ H, const unsigned* __restrict__ num,
    const float* __restrict__ den,
    const float* __restrict__ gamma, const float* __restrict__ beta,
    float* __restrict__ out)
{
    const int w = threadIdx.x >> 6;
    const int l = threadIdx.x & 63;
    const long row = (long)blockIdx.x * 4 + w;
    const int hh = l >> 4, cc = l & 15;
    const int c_lo = hh * 32 + cc, c_hi = c_lo + 16;
    const float hx = H[row * DD + c_lo];
    const float hy = H[row * DD + c_hi];

    float ax = 0.f, ay = 0.f;
#pragma unroll
    for (int r = 0; r < RR; ++r) {
        float dsum = 0.f, nx = 0.f, ny = 0.f;
#pragma unroll
        for (int j = 0; j < 4; ++j) {
            const long ro = (long)(r * 4 + j) * (BB * NN) + row;
            dsum += den[ro * HH + hh];
            const unsigned wv = num[ro * 64 + l];
            nx += __uint_as_float(wv << 16);
            ny += __uint_as_float(wv & 0xffff0000u);
        }
        const float inv = (dsum > 0.f) ? 1.0f / dsum : 0.0f;
        ax = fmaf(nx, inv, ax);
        ay = fmaf(ny, inv, ay);
    }
    const float x0 = hx + ax * (1.0f / RR);
    const float x1 = hy + ay * (1.0f / RR);
    float s = x0 + x1, q = x0 * x0 + x1 * x1;
#pragma unroll
    for (int m = 1; m < 64; m <<= 1) {
        s += __shfl_xor(s, m);
        q += __shfl_xor(q, m);
    }
    const float mu  = s * (1.0f / DD);
    const float var = q * (1.0f / DD) - mu * mu;
    const float inv = rsqrtf(var + LN_EPS);
    out[row * DD + c_lo] = (x0 - mu) * inv * gamma[c_lo] + beta[c_lo];
    out[row * DD + c_hi] = (x1 - mu) * inv * gamma[c_hi] + beta[c_hi];
}

// ---------------------------------------------------------------------------
extern "C" void kernel_launch(void* const* d_in, const int* in_sizes, int n_in,
                              void* d_out, int out_size, void* d_ws, size_t ws_size,
                              hipStream_t stream)
{
    const float* H      = (const float*)d_in[0];
    const int*   A      = (const int*)d_in[1];
    const float* W      = (const float*)d_in[2];
    const float* a_src  = (const float*)d_in[3];
    const float* a_dst  = (const float*)d_in[4];
    const float* gamma  = (const float*)d_in[5];
    const float* beta   = (const float*)d_in[6];
    float* out = (float*)d_out;

    // workspace carve (~20.1 MB; ws_size ~400 MB per harness poison-fill)
    char* ws = (char*)d_ws;
    unsigned* num = (unsigned*)ws;               ws += (size_t)RR * 4 * BB * NN * 64 * 4;  // 12.6 MB
    float* den = (float*)ws;                     ws += (size_t)RR * 4 * BB * NN * HH * 4;  // 786 KB
    float* es  = (float*)ws;                     ws += (size_t)RR * BB * HH * NN * 4;      // 196 KB
    float* ed  = (float*)ws;                     ws += (size_t)RR * BB * HH * NN * 4;      // 196 KB
    __hip_bfloat16* whT = (__hip_bfloat16*)ws;   ws += (size_t)RR * BB * HH * HD * NN * 2; // 3.15 MB
    unsigned* bmask = (unsigned*)ws;             ws += (size_t)RR * BB * NN * (NN / 32) * 4; // 3.15 MB

    prep_kernel<<<384 + RR * BB * NN * (NN / 32) / 256, 256, 0, stream>>>(
        H, A, W, a_src, a_dst, es, ed, whT, bmask);
    gat_attn_kernel<<<RR * BB * HH * 16 * 4, 256, 0, stream>>>(bmask, es, ed, whT, num, den);
    finalize_kernel<<<BB * NN / 4, 256, 0, stream>>>(H, num, den, gamma, beta, out);
}

// Round 20
// 64.713 us; speedup vs baseline: 1.5782x; 1.1234x over previous
//
#include <hip/hip_runtime.h>
#include <hip/hip_bf16.h>

// Problem constants (from reference setup_inputs)
#define RR 3
#define BB 2
#define NN 2048
#define DD 128
#define HH 4
#define HD 32
#define LEAKY 0.2f
#define LN_EPS 1e-5f
#define LOG2E 1.4426950408889634f

using f32x4  = __attribute__((ext_vector_type(4))) float;
using bf16x8 = __attribute__((ext_vector_type(8))) short;

__device__ __forceinline__ void gload_lds16(const void* g, void* l) {
    __builtin_amdgcn_global_load_lds(
        (const __attribute__((address_space(1))) unsigned*)g,
        (__attribute__((address_space(3))) unsigned*)l, 16, 0, 0);
}
__device__ __forceinline__ void gload_lds4(const void* g, void* l) {
    __builtin_amdgcn_global_load_lds(
        (const __attribute__((address_space(1))) unsigned*)g,
        (__attribute__((address_space(3))) unsigned*)l, 4, 0, 0);
}
__device__ __forceinline__ unsigned short bfb(float x) {
    return __builtin_bit_cast(unsigned short, __float2bfloat16(x));
}

// ---------------------------------------------------------------------------
// Layouts (both producer- AND consumer-coalesced):
//  whT tiled: [rbh][S 0..15][jc 4][kg 4][f 32][e 8] bf16 — 8KB tile = the
//    exact whs LDS image for stage S. gat stages it with dense gload_lds16.
//  bm transposed: [rb 6][wordidx 0..63][nrow 0..2047] u32. Word semantics
//    unchanged: word (e,q,h): bit i <-> j = e*256 + h*128 + 4i + q,
//    wordidx = e*8 + q*2 + h. Stage S, wave w needs plane
//    woff = (S>>1)*8 + (S&1) + w*2, rows i0..i0+127 -> 512B contiguous.
// ---------------------------------------------------------------------------

// ---------------------------------------------------------------------------
// Kernel 1: fused prep. grid = 768 compact + 384 wh = 1152 blocks.
//  - bid<768: compact. Block = 16 A-rows; per wave 4 row-iterations
//    (8 int4 loads -> 4 ballots x8 -> lane l holds wordidx l), transpose
//    through padded LDS, store bm planes as full 64B lines.
//  - bid>=768: wh via MFMA; writes whT in tiled layout + es/ed (log2e).
// ---------------------------------------------------------------------------
__global__ __launch_bounds__(256) void prep_kernel(
    const float* __restrict__ H, const int* __restrict__ A,
    const float* __restrict__ W,
    const float* __restrict__ a_src, const float* __restrict__ a_dst,
    float* __restrict__ es, float* __restrict__ ed,
    __hip_bfloat16* __restrict__ whT, unsigned* __restrict__ bm)
{
    __shared__ unsigned cb_lds[16][65];   // padded transpose buffer (4.2KB)

    const int bid = blockIdx.x;
    const int t = threadIdx.x;
    const int w = t >> 6;
    const int l = t & 63;

    if (bid < 768) {
        // ---- compact role: 16 rows, ballot -> LDS transpose -> lines ----
        const int sel_e = l >> 3;
        const int sel_q = (l >> 1) & 3;
        const int sel_h = l & 1;
#pragma unroll
        for (int iter = 0; iter < 4; ++iter) {
            const int lr = iter * 4 + w;                 // local row 0..15
            const long crow = (long)bid * 16 + lr;       // flat A row
            const int4* Ap = (const int4*)A + crow * 512 + l;
            int4 v[8];
#pragma unroll
            for (int e = 0; e < 8; ++e) v[e] = Ap[e * 64];
            unsigned word = 0;
#pragma unroll
            for (int e = 0; e < 8; ++e) {
                const unsigned long long B0 = __ballot(v[e].x != 0);
                const unsigned long long B1 = __ballot(v[e].y != 0);
                const unsigned long long B2 = __ballot(v[e].z != 0);
                const unsigned long long B3 = __ballot(v[e].w != 0);
                if (sel_e == e) {
                    const unsigned long long Bq =
                        (sel_q == 3) ? B3 : (sel_q == 2) ? B2 : (sel_q == 1) ? B1 : B0;
                    word = sel_h ? (unsigned)(Bq >> 32) : (unsigned)Bq;
                }
            }
            cb_lds[lr][l] = word;                        // wordidx == lane
        }
        __syncthreads();
        // store: plane p = t>>2, chunk c = t&3 -> 16B; 4 threads = 64B line
        {
            const long nrow0g = (long)bid * 16;
            const int rb = (int)(nrow0g >> 11);
            const int nrow0 = (int)(nrow0g & 2047);
            const int p = t >> 2, c = t & 3;
            uint4 val;
            val.x = cb_lds[c * 4 + 0][p];
            val.y = cb_lds[c * 4 + 1][p];
            val.z = cb_lds[c * 4 + 2][p];
            val.w = cb_lds[c * 4 + 3][p];
            *(uint4*)(bm + ((long)rb * 64 + p) * 2048 + nrow0 + c * 4) = val;
        }
        return;
    }

    // ---- wh role ----
    const int wb = bid - 768;          // 0..383
    const int rbh = wb >> 4;           // (r*BB+b)*HH+h
    const int nch = wb & 15;           // 128-col chunk (= tile S)
    const int h = rbh & 3;
    const int b = (rbh >> 2) & 1;
    const int r = rbh >> 3;
    const int wi = r * HH + h;
    const int lr = l & 15;
    const int lg = l >> 4;

    const float* Wp = W + (long)wi * DD * HD;
    bf16x8 afr[2][4];
#pragma unroll
    for (int mt = 0; mt < 2; ++mt)
#pragma unroll
        for (int kt = 0; kt < 4; ++kt)
#pragma unroll
            for (int e = 0; e < 8; ++e)
                afr[mt][kt][e] = (short)bfb(Wp[(kt * 32 + lg * 8 + e) * HD + mt * 16 + lr]);

    float av[2][4], dv[2][4];
#pragma unroll
    for (int mt = 0; mt < 2; ++mt)
#pragma unroll
        for (int reg = 0; reg < 4; ++reg) {
            const int f = mt * 16 + lg * 4 + reg;
            av[mt][reg] = a_src[wi * HD + f] * LOG2E;
            dv[mt][reg] = a_dst[wi * HD + f] * LOG2E;
        }

    __hip_bfloat16* tile = whT + ((long)rbh * 16 + nch) * 4096;

#pragma unroll
    for (int nt = 0; nt < 2; ++nt) {
        const int ncol = nch * 128 + w * 32 + nt * 16 + lr;
        const float4* hrow4 = (const float4*)(H + ((long)b * NN + ncol) * DD);
        f32x4 acc0 = {0.f, 0.f, 0.f, 0.f};
        f32x4 acc1 = {0.f, 0.f, 0.f, 0.f};
#pragma unroll
        for (int kt = 0; kt < 4; ++kt) {
            float4 h0 = hrow4[kt * 8 + lg * 2];
            float4 h1 = hrow4[kt * 8 + lg * 2 + 1];
            bf16x8 bfr;
            bfr[0] = (short)bfb(h0.x); bfr[1] = (short)bfb(h0.y);
            bfr[2] = (short)bfb(h0.z); bfr[3] = (short)bfb(h0.w);
            bfr[4] = (short)bfb(h1.x); bfr[5] = (short)bfb(h1.y);
            bfr[6] = (short)bfb(h1.z); bfr[7] = (short)bfb(h1.w);
            acc0 = __builtin_amdgcn_mfma_f32_16x16x32_bf16(afr[0][kt], bfr, acc0, 0, 0, 0);
            acc1 = __builtin_amdgcn_mfma_f32_16x16x32_bf16(afr[1][kt], bfr, acc1, 0, 0, 0);
        }
        // tiled whT write: [jc=w][kg=nt*2+(lr>>3)][f][e=lr&7]
        const int kgw = nt * 2 + (lr >> 3);
        const int ew = lr & 7;
        float s = 0.f, d = 0.f;
#pragma unroll
        for (int reg = 0; reg < 4; ++reg) {
            const int f0 = lg * 4 + reg;
            const int f1 = 16 + lg * 4 + reg;
            tile[((w * 4 + kgw) * 32 + f0) * 8 + ew] = __float2bfloat16(acc0[reg]);
            tile[((w * 4 + kgw) * 32 + f1) * 8 + ew] = __float2bfloat16(acc1[reg]);
            s = fmaf(acc0[reg], av[0][reg], s);
            s = fmaf(acc1[reg], av[1][reg], s);
            d = fmaf(acc0[reg], dv[0][reg], d);
            d = fmaf(acc1[reg], dv[1][reg], d);
        }
        s += __shfl_xor(s, 16); s += __shfl_xor(s, 32);
        d += __shfl_xor(d, 16); d += __shfl_xor(d, 32);
        if (l < 16) {
            es[(long)rbh * NN + ncol] = s;
            ed[(long)rbh * NN + ncol] = d;
        }
    }
}

// ---------------------------------------------------------------------------
// Kernel 2: fused masked softmax + MFMA aggregation (JS=2, R14 structure)
// with fully-coalesced staging: whT tiles (2x dense 1KB gload/wave) and
// transposed bm planes (1x dense 512B gload/wave). vmcnt(4).
// grid = 768 blocks (XCD swizzled), 256 threads.
// ---------------------------------------------------------------------------
__global__ __launch_bounds__(256, 3) void gat_attn_kernel(
    const unsigned* __restrict__ bm, const float* __restrict__ es,
    const float* __restrict__ ed, const __hip_bfloat16* __restrict__ whT,
    unsigned* __restrict__ num, float* __restrict__ den)
{
    const int lg = ((int)blockIdx.x % 8) * 96 + (int)blockIdx.x / 8;
    const int jh = lg & 1;
    const int it = (lg >> 1) & 15;
    const int h  = (lg >> 5) & 3;
    const int b  = (lg >> 7) & 1;
    const int r  = lg >> 8;
    const int i0 = it << 7;
    const int tid = threadIdx.x;
    const int w = tid >> 6;
    const int l = tid & 63;
    const int row = l & 15;
    const int kg  = l >> 4;

    __shared__ __align__(16) short    whs[2][4][4][32][8];
    __shared__ __align__(16) unsigned bms[2][4][128];
    __shared__ __align__(16) float    eds[2][4][32];
    __shared__ float red[4];

    const int rbh = (r * BB + b) * HH + h;
    const long rbNN = (long)(r * BB + b) * NN;
    const float* edr = ed + (long)rbh * NN;
    const int jbase = jh * (NN / 2);

#define STAGE(s, nb) do {                                                           \
        const int S_ = jh * 8 + (s);                                                \
        const __hip_bfloat16* tsrc = whT + ((long)rbh * 16 + S_) * 4096;            \
        short* wdst = &whs[nb][0][0][0][0] + w * 1024;                              \
        gload_lds16(tsrc + w * 1024 + l * 8, wdst);                                 \
        gload_lds16(tsrc + w * 1024 + 512 + l * 8, wdst + 512);                     \
        const int woff_ = (S_ >> 1) * 8 + (S_ & 1) + w * 2;                         \
        if (l < 32) gload_lds16(bm + rbNN * 64 + (long)woff_ * 2048 + i0 + l * 4,   \
                                &bms[nb][w][0]);                                    \
        if (l < 32) gload_lds4(edr + jbase + (s) * 128 + w * 32 + l,                \
                               &eds[nb][w][0]);                                     \
    } while (0)

    STAGE(0, 0);

    // block-wide max of ed (upper bound; cancels exactly in num/den)
    float4 m0 = ((const float4*)edr)[tid * 2];
    float4 m1 = ((const float4*)edr)[tid * 2 + 1];
    float mm = fmaxf(fmaxf(fmaxf(m0.x, m0.y), fmaxf(m0.z, m0.w)),
                     fmaxf(fmaxf(m1.x, m1.y), fmaxf(m1.z, m1.w)));
#pragma unroll
    for (int d = 1; d < 64; d <<= 1) mm = fmaxf(mm, __shfl_xor(mm, d));
    if (l == 0) red[w] = mm;
    __syncthreads();
    const float medf = fmaxf(fmaxf(red[0], red[1]), fmaxf(red[2], red[3]));

    const float esvA = es[(long)rbh * NN + i0 + w * 16 + row];
    const float esvB = es[(long)rbh * NN + i0 + 64 + w * 16 + row];
    const float xA = esvA + medf, xB = esvB + medf;
    const float MA = fmaxf(xA, LEAKY * xA), MB = fmaxf(xB, LEAKY * xB);
    const float uA = esvA - MA, vA = fmaf(LEAKY, esvA, -MA);
    const float uB = esvB - MB, vB = fmaf(LEAKY, esvB, -MB);

    f32x4 acc0A = {0,0,0,0}, acc1A = {0,0,0,0}, accDA = {0,0,0,0};
    f32x4 acc0B = {0,0,0,0}, acc1B = {0,0,0,0}, accDB = {0,0,0,0};
    bf16x8 ones;
#pragma unroll
    for (int i = 0; i < 8; ++i) ones[i] = (short)0x3F80;

    const int kk = kg * 2;
    const int rAi = w * 16 + row, rBi = 64 + w * 16 + row;

    for (int s = 0; s < 8; ++s) {
        const int cb = s & 1, nb = cb ^ 1;
        if (s < 7) {
            STAGE(s + 1, nb);
            asm volatile("s_waitcnt vmcnt(4)" ::: "memory");
        } else {
            asm volatile("s_waitcnt vmcnt(0)" ::: "memory");
        }
        __builtin_amdgcn_s_barrier();
        __builtin_amdgcn_sched_barrier(0);

        unsigned wA[4], wB[4];
#pragma unroll
        for (int q = 0; q < 4; ++q) {
            wA[q] = bms[cb][q][rAi];
            wB[q] = bms[cb][q][rBi];
        }

#pragma unroll
        for (int jc = 0; jc < 4; ++jc) {
            bf16x8 b0 = *(const bf16x8*)&whs[cb][jc][kg][row][0];
            bf16x8 b1 = *(const bf16x8*)&whs[cb][jc][kg][row + 16][0];
            float4 e0 = *(const float4*)&eds[cb][jc][kg * 8];
            float4 e1 = *(const float4*)&eds[cb][jc][kg * 8 + 4];

            unsigned uAq[4], uBq[4];
#pragma unroll
            for (int q = 0; q < 4; ++q) {
                uAq[q] = wA[q] >> (jc * 8 + kk);
                uBq[q] = wB[q] >> (jc * 8 + kk);
            }

            float ev[8];
            ev[0] = e0.x; ev[1] = e0.y; ev[2] = e0.z; ev[3] = e0.w;
            ev[4] = e1.x; ev[5] = e1.y; ev[6] = e1.z; ev[7] = e1.w;

            bf16x8 pA, pB;
#pragma unroll
            for (int c = 0; c < 8; ++c) {
                float pa = __builtin_amdgcn_exp2f(
                    fmaxf(uA + ev[c], fmaf(LEAKY, ev[c], vA)));
                float pb = __builtin_amdgcn_exp2f(
                    fmaxf(uB + ev[c], fmaf(LEAKY, ev[c], vB)));
                const int ma = ((int)(uAq[c & 3] << (31 - (c >> 2)))) >> 31;
                const int mb = ((int)(uBq[c & 3] << (31 - (c >> 2)))) >> 31;
                pa = __uint_as_float(__float_as_uint(pa) & (unsigned)ma);
                pb = __uint_as_float(__float_as_uint(pb) & (unsigned)mb);
                __hip_bfloat16 ha = __float2bfloat16(pa);
                __hip_bfloat16 hb = __float2bfloat16(pb);
                pA[c] = __builtin_bit_cast(short, ha);
                pB[c] = __builtin_bit_cast(short, hb);
            }

            __builtin_amdgcn_s_setprio(1);
            acc0A = __builtin_amdgcn_mfma_f32_16x16x32_bf16(pA, b0, acc0A, 0, 0, 0);
            acc1A = __builtin_amdgcn_mfma_f32_16x16x32_bf16(pA, b1, acc1A, 0, 0, 0);
            accDA = __builtin_amdgcn_mfma_f32_16x16x32_bf16(pA, ones, accDA, 0, 0, 0);
            acc0B = __builtin_amdgcn_mfma_f32_16x16x32_bf16(pB, b0, acc0B, 0, 0, 0);
            acc1B = __builtin_amdgcn_mfma_f32_16x16x32_bf16(pB, b1, acc1B, 0, 0, 0);
            accDB = __builtin_amdgcn_mfma_f32_16x16x32_bf16(pB, ones, accDB, 0, 0, 0);
            __builtin_amdgcn_s_setprio(0);
        }
        __builtin_amdgcn_s_barrier();
        __builtin_amdgcn_sched_barrier(0);
    }
#undef STAGE

    const int fcol = l & 15;
    const int pr = r * 2 + jh;
#pragma unroll
    for (int reg = 0; reg < 4; ++reg) {
        const int orow = (l >> 4) * 4 + reg;
        const long roA = (long)pr * (BB * NN) + (long)b * NN + i0 + w * 16 + orow;
        const long roB = roA + 64;
        const unsigned wa = (unsigned)bfb(acc0A[reg]) | ((unsigned)bfb(acc1A[reg]) << 16);
        const unsigned wb_ = (unsigned)bfb(acc0B[reg]) | ((unsigned)bfb(acc1B[reg]) << 16);
        num[roA * 64 + h * 16 + fcol] = wa;
        num[roB * 64 + h * 16 + fcol] = wb_;
        if (fcol == 0) {
            den[roA * HH + h] = accDA[reg];
            den[roB * HH + h] = accDB[reg];
        }
    }
}

// ---------------------------------------------------------------------------
// Kernel 3: out = LayerNorm(H + mean_r (num_r / den_r)); 2 j-chunks.
// ---------------------------------------------------------------------------
__global__ __launch_bounds__(256) void finalize_kernel(
    const float* __restrict__ H, const unsigned* __restrict__ num,
    const float* __restrict__ den,
    const float* __restrict__ gamma, const float* __restrict__ beta,
    float* __restrict__ out)
{
    const int w = threadIdx.x >> 6;
    const int l = threadIdx.x & 63;
    const long row = (long)blockIdx.x * 4 + w;
    const int hh = l >> 4, cc = l & 15;
    const int c_lo = hh * 32 + cc, c_hi = c_lo + 16;
    const float hx = H[row * DD + c_lo];
    const float hy = H[row * DD + c_hi];

    float ax = 0.f, ay = 0.f;
#pragma unroll
    for (int r = 0; r < RR; ++r) {
        float dsum = 0.f, nx = 0.f, ny = 0.f;
#pragma unroll
        for (int j = 0; j < 2; ++j) {
            const long ro = (long)(r * 2 + j) * (BB * NN) + row;
            dsum += den[ro * HH + hh];
            const unsigned wv = num[ro * 64 + l];
            nx += __uint_as_float(wv << 16);
            ny += __uint_as_float(wv & 0xffff0000u);
        }
        const float inv = (dsum > 0.f) ? 1.0f / dsum : 0.0f;
        ax = fmaf(nx, inv, ax);
        ay = fmaf(ny, inv, ay);
    }
    const float x0 = hx + ax * (1.0f / RR);
    const float x1 = hy + ay * (1.0f / RR);
    float s = x0 + x1, q = x0 * x0 + x1 * x1;
#pragma unroll
    for (int m = 1; m < 64; m <<= 1) {
        s += __shfl_xor(s, m);
        q += __shfl_xor(q, m);
    }
    const float mu  = s * (1.0f / DD);
    const float var = q * (1.0f / DD) - mu * mu;
    const float inv = rsqrtf(var + LN_EPS);
    out[row * DD + c_lo] = (x0 - mu) * inv * gamma[c_lo] + beta[c_lo];
    out[row * DD + c_hi] = (x1 - mu) * inv * gamma[c_hi] + beta[c_hi];
}

// ---------------------------------------------------------------------------
extern "C" void kernel_launch(void* const* d_in, const int* in_sizes, int n_in,
                              void* d_out, int out_size, void* d_ws, size_t ws_size,
                              hipStream_t stream)
{
    const float* H      = (const float*)d_in[0];
    const int*   A      = (const int*)d_in[1];
    const float* W      = (const float*)d_in[2];
    const float* a_src  = (const float*)d_in[3];
    const float* a_dst  = (const float*)d_in[4];
    const float* gamma  = (const float*)d_in[5];
    const float* beta   = (const float*)d_in[6];
    float* out = (float*)d_out;

    // workspace carve (~13.4 MB)
    char* ws = (char*)d_ws;
    unsigned* num = (unsigned*)ws;               ws += (size_t)RR * 2 * BB * NN * 64 * 4;
    float* den = (float*)ws;                     ws += (size_t)RR * 2 * BB * NN * HH * 4;
    float* es  = (float*)ws;                     ws += (size_t)RR * BB * HH * NN * 4;
    float* ed  = (float*)ws;                     ws += (size_t)RR * BB * HH * NN * 4;
    __hip_bfloat16* whT = (__hip_bfloat16*)ws;   ws += (size_t)RR * BB * HH * HD * NN * 2;
    unsigned* bmask = (unsigned*)ws;             ws += (size_t)RR * BB * NN * (NN / 32) * 4;

    prep_kernel<<<768 + 384, 256, 0, stream>>>(
        H, A, W, a_src, a_dst, es, ed, whT, bmask);
    gat_attn_kernel<<<RR * BB * HH * 16 * 2, 256, 0, stream>>>(bmask, es, ed, whT, num, den);
    finalize_kernel<<<BB * NN / 4, 256, 0, stream>>>(H, num, den, gamma, beta, out);
}

// Round 21
// 63.667 us; speedup vs baseline: 1.6041x; 1.0164x over previous
//
#include <hip/hip_runtime.h>
#include <hip/hip_bf16.h>

// Problem constants (from reference setup_inputs)
#define RR 3
#define BB 2
#define NN 2048
#define DD 128
#define HH 4
#define HD 32
#define LEAKY 0.2f
#define LN_EPS 1e-5f
#define LOG2E 1.4426950408889634f

using f32x4  = __attribute__((ext_vector_type(4))) float;
using bf16x8 = __attribute__((ext_vector_type(8))) short;

__device__ __forceinline__ unsigned short bfb(float x) {
    return __builtin_bit_cast(unsigned short, __float2bfloat16(x));
}

// ---------------------------------------------------------------------------
// Layouts (proven correct in R20 run):
//  whT tiled: [rbh][S 0..15][jc 4][kg 4][f 32][e 8] bf16 — 8KB per 128-j
//    segment; b0/b1 fragment reads are fully dense 1KB wave-loads.
//  bm transposed: [rb 6][wordidx 0..63][nrow 0..2047] u32; word (e,q,h):
//    bit i <-> j = e*256 + h*128 + 4i + q; wordidx = e*8 + q*2 + h.
//    Mask bit for col c of jc: bit (c>>2) of (word[c&3] >> (jc*8 + kg*2)).
// ---------------------------------------------------------------------------

// ---------------------------------------------------------------------------
// Kernel 1: fused prep (byte-identical to R20's proven version).
// grid = 768 compact + 384 wh = 1152 blocks.
// ---------------------------------------------------------------------------
__global__ __launch_bounds__(256) void prep_kernel(
    const float* __restrict__ H, const int* __restrict__ A,
    const float* __restrict__ W,
    const float* __restrict__ a_src, const float* __restrict__ a_dst,
    float* __restrict__ es, float* __restrict__ ed,
    __hip_bfloat16* __restrict__ whT, unsigned* __restrict__ bm)
{
    __shared__ unsigned cb_lds[16][65];   // padded transpose buffer

    const int bid = blockIdx.x;
    const int t = threadIdx.x;
    const int w = t >> 6;
    const int l = t & 63;

    if (bid < 768) {
        // ---- compact role: 16 rows, ballot -> LDS transpose -> lines ----
        const int sel_e = l >> 3;
        const int sel_q = (l >> 1) & 3;
        const int sel_h = l & 1;
#pragma unroll
        for (int iter = 0; iter < 4; ++iter) {
            const int lr = iter * 4 + w;
            const long crow = (long)bid * 16 + lr;
            const int4* Ap = (const int4*)A + crow * 512 + l;
            int4 v[8];
#pragma unroll
            for (int e = 0; e < 8; ++e) v[e] = Ap[e * 64];
            unsigned word = 0;
#pragma unroll
            for (int e = 0; e < 8; ++e) {
                const unsigned long long B0 = __ballot(v[e].x != 0);
                const unsigned long long B1 = __ballot(v[e].y != 0);
                const unsigned long long B2 = __ballot(v[e].z != 0);
                const unsigned long long B3 = __ballot(v[e].w != 0);
                if (sel_e == e) {
                    const unsigned long long Bq =
                        (sel_q == 3) ? B3 : (sel_q == 2) ? B2 : (sel_q == 1) ? B1 : B0;
                    word = sel_h ? (unsigned)(Bq >> 32) : (unsigned)Bq;
                }
            }
            cb_lds[lr][l] = word;
        }
        __syncthreads();
        {
            const long nrow0g = (long)bid * 16;
            const int rb = (int)(nrow0g >> 11);
            const int nrow0 = (int)(nrow0g & 2047);
            const int p = t >> 2, c = t & 3;
            uint4 val;
            val.x = cb_lds[c * 4 + 0][p];
            val.y = cb_lds[c * 4 + 1][p];
            val.z = cb_lds[c * 4 + 2][p];
            val.w = cb_lds[c * 4 + 3][p];
            *(uint4*)(bm + ((long)rb * 64 + p) * 2048 + nrow0 + c * 4) = val;
        }
        return;
    }

    // ---- wh role ----
    const int wb = bid - 768;
    const int rbh = wb >> 4;
    const int nch = wb & 15;
    const int h = rbh & 3;
    const int b = (rbh >> 2) & 1;
    const int r = rbh >> 3;
    const int wi = r * HH + h;
    const int lr = l & 15;
    const int lg = l >> 4;

    const float* Wp = W + (long)wi * DD * HD;
    bf16x8 afr[2][4];
#pragma unroll
    for (int mt = 0; mt < 2; ++mt)
#pragma unroll
        for (int kt = 0; kt < 4; ++kt)
#pragma unroll
            for (int e = 0; e < 8; ++e)
                afr[mt][kt][e] = (short)bfb(Wp[(kt * 32 + lg * 8 + e) * HD + mt * 16 + lr]);

    float av[2][4], dv[2][4];
#pragma unroll
    for (int mt = 0; mt < 2; ++mt)
#pragma unroll
        for (int reg = 0; reg < 4; ++reg) {
            const int f = mt * 16 + lg * 4 + reg;
            av[mt][reg] = a_src[wi * HD + f] * LOG2E;
            dv[mt][reg] = a_dst[wi * HD + f] * LOG2E;
        }

    __hip_bfloat16* tile = whT + ((long)rbh * 16 + nch) * 4096;

#pragma unroll
    for (int nt = 0; nt < 2; ++nt) {
        const int ncol = nch * 128 + w * 32 + nt * 16 + lr;
        const float4* hrow4 = (const float4*)(H + ((long)b * NN + ncol) * DD);
        f32x4 acc0 = {0.f, 0.f, 0.f, 0.f};
        f32x4 acc1 = {0.f, 0.f, 0.f, 0.f};
#pragma unroll
        for (int kt = 0; kt < 4; ++kt) {
            float4 h0 = hrow4[kt * 8 + lg * 2];
            float4 h1 = hrow4[kt * 8 + lg * 2 + 1];
            bf16x8 bfr;
            bfr[0] = (short)bfb(h0.x); bfr[1] = (short)bfb(h0.y);
            bfr[2] = (short)bfb(h0.z); bfr[3] = (short)bfb(h0.w);
            bfr[4] = (short)bfb(h1.x); bfr[5] = (short)bfb(h1.y);
            bfr[6] = (short)bfb(h1.z); bfr[7] = (short)bfb(h1.w);
            acc0 = __builtin_amdgcn_mfma_f32_16x16x32_bf16(afr[0][kt], bfr, acc0, 0, 0, 0);
            acc1 = __builtin_amdgcn_mfma_f32_16x16x32_bf16(afr[1][kt], bfr, acc1, 0, 0, 0);
        }
        const int kgw = nt * 2 + (lr >> 3);
        const int ew = lr & 7;
        float s = 0.f, d = 0.f;
#pragma unroll
        for (int reg = 0; reg < 4; ++reg) {
            const int f0 = lg * 4 + reg;
            const int f1 = 16 + lg * 4 + reg;
            tile[((w * 4 + kgw) * 32 + f0) * 8 + ew] = __float2bfloat16(acc0[reg]);
            tile[((w * 4 + kgw) * 32 + f1) * 8 + ew] = __float2bfloat16(acc1[reg]);
            s = fmaf(acc0[reg], av[0][reg], s);
            s = fmaf(acc1[reg], av[1][reg], s);
            d = fmaf(acc0[reg], dv[0][reg], d);
            d = fmaf(acc1[reg], dv[1][reg], d);
        }
        s += __shfl_xor(s, 16); s += __shfl_xor(s, 32);
        d += __shfl_xor(d, 16); d += __shfl_xor(d, 32);
        if (l < 16) {
            es[(long)rbh * NN + ncol] = s;
            ed[(long)rbh * NN + ncol] = d;
        }
    }
}

// ---------------------------------------------------------------------------
// Kernel 2: BARRIER-FREE fused masked softmax + MFMA aggregation.
// block = (r, b, 16-row i-tile, j-half); 4 waves = 4 heads, fully
// independent: no LDS tiles, no s_barrier, no manual waitcnt — loads go
// straight to VGPRs from the coalesced tiled whT / transposed bm and the
// compiler software-pipelines across jc. Per-wave ed-max (identical across
// jh halves -> consistent num/den normalization).
// grid = R*B*128*2 = 1536 blocks (XCD swizzled), 24 waves/CU.
// ---------------------------------------------------------------------------
__global__ __launch_bounds__(256, 6) void gat_attn_kernel(
    const unsigned* __restrict__ bm, const float* __restrict__ es,
    const float* __restrict__ ed, const __hip_bfloat16* __restrict__ whT,
    unsigned* __restrict__ num, float* __restrict__ den)
{
    const int lg = ((int)blockIdx.x % 8) * 192 + (int)blockIdx.x / 8;
    const int jh = lg & 1;
    const int it = (lg >> 1) & 127;        // 16-row i-tile
    const int b  = (lg >> 8) & 1;
    const int r  = lg >> 9;
    const int i0 = it << 4;
    const int tid = threadIdx.x;
    const int h = tid >> 6;                // wave = head
    const int l = tid & 63;
    const int row = l & 15;
    const int kg  = l >> 4;

    const int rb  = r * BB + b;
    const int rbh = rb * HH + h;
    const float* edr = ed + (long)rbh * NN;

    // per-wave max of ed over all 2048 j (upper bound; cancels in num/den)
    float mm = -1e30f;
#pragma unroll
    for (int k = 0; k < 8; ++k) {
        float4 v = ((const float4*)edr)[k * 64 + l];
        mm = fmaxf(mm, fmaxf(fmaxf(v.x, v.y), fmaxf(v.z, v.w)));
    }
#pragma unroll
    for (int d = 1; d < 64; d <<= 1) mm = fmaxf(mm, __shfl_xor(mm, d));

    const float esv = es[(long)rbh * NN + i0 + row];   // log2e-scaled
    const float x = esv + mm;
    const float M = fmaxf(x, LEAKY * x);
    const float uA = esv - M;
    const float vA = fmaf(LEAKY, esv, -M);

    f32x4 acc0 = {0,0,0,0}, acc1 = {0,0,0,0}, accD = {0,0,0,0};
    bf16x8 ones;
#pragma unroll
    for (int i = 0; i < 8; ++i) ones[i] = (short)0x3F80;

    const int kk = kg * 2;
    const unsigned* bmb = bm + (long)rb * 64 * 2048 + i0 + row;

#pragma unroll 1
    for (int seg = 0; seg < 8; ++seg) {
        const int S = jh * 8 + seg;
        const __hip_bfloat16* tile = whT + ((long)rbh * 16 + S) * 4096;
        const int wbase = (S >> 1) * 8 + (S & 1);
        unsigned wA[4];
#pragma unroll
        for (int q = 0; q < 4; ++q)
            wA[q] = bmb[(long)(wbase + q * 2) * 2048];
        const float* edseg = edr + S * 128;

#pragma unroll
        for (int jc = 0; jc < 4; ++jc) {
            bf16x8 b0 = *(const bf16x8*)(tile + jc * 1024 + kg * 256 + row * 8);
            bf16x8 b1 = *(const bf16x8*)(tile + jc * 1024 + kg * 256 + 128 + row * 8);
            float4 e0 = *(const float4*)(edseg + jc * 32 + kg * 8);
            float4 e1 = *(const float4*)(edseg + jc * 32 + kg * 8 + 4);

            unsigned uq[4];
#pragma unroll
            for (int q = 0; q < 4; ++q) uq[q] = wA[q] >> (jc * 8 + kk);

            float ev[8];
            ev[0] = e0.x; ev[1] = e0.y; ev[2] = e0.z; ev[3] = e0.w;
            ev[4] = e1.x; ev[5] = e1.y; ev[6] = e1.z; ev[7] = e1.w;

            bf16x8 p;
#pragma unroll
            for (int c = 0; c < 8; ++c) {
                float pa = __builtin_amdgcn_exp2f(
                    fmaxf(uA + ev[c], fmaf(LEAKY, ev[c], vA)));
                const int ma = ((int)(uq[c & 3] << (31 - (c >> 2)))) >> 31;
                pa = __uint_as_float(__float_as_uint(pa) & (unsigned)ma);
                __hip_bfloat16 ha = __float2bfloat16(pa);
                p[c] = __builtin_bit_cast(short, ha);
            }

            __builtin_amdgcn_s_setprio(1);
            acc0 = __builtin_amdgcn_mfma_f32_16x16x32_bf16(p, b0, acc0, 0, 0, 0);
            acc1 = __builtin_amdgcn_mfma_f32_16x16x32_bf16(p, b1, acc1, 0, 0, 0);
            accD = __builtin_amdgcn_mfma_f32_16x16x32_bf16(p, ones, accD, 0, 0, 0);
            __builtin_amdgcn_s_setprio(0);
        }
    }

    // epilogue: packed bf16 numerators + fp32 denominators
    const int fcol = l & 15;
    const int pr = r * 2 + jh;
#pragma unroll
    for (int reg = 0; reg < 4; ++reg) {
        const int orow = (l >> 4) * 4 + reg;
        const long ro = (long)pr * (BB * NN) + (long)b * NN + i0 + orow;
        num[ro * 64 + h * 16 + fcol] =
            (unsigned)bfb(acc0[reg]) | ((unsigned)bfb(acc1[reg]) << 16);
        if (fcol == 0) den[ro * HH + h] = accD[reg];
    }
}

// ---------------------------------------------------------------------------
// Kernel 3: out = LayerNorm(H + mean_r (num_r / den_r)); 2 j-chunks.
// ---------------------------------------------------------------------------
__global__ __launch_bounds__(256) void finalize_kernel(
    const float* __restrict__ H, const unsigned* __restrict__ num,
    const float* __restrict__ den,
    const float* __restrict__ gamma, const float* __restrict__ beta,
    float* __restrict__ out)
{
    const int w = threadIdx.x >> 6;
    const int l = threadIdx.x & 63;
    const long row = (long)blockIdx.x * 4 + w;
    const int hh = l >> 4, cc = l & 15;
    const int c_lo = hh * 32 + cc, c_hi = c_lo + 16;
    const float hx = H[row * DD + c_lo];
    const float hy = H[row * DD + c_hi];

    float ax = 0.f, ay = 0.f;
#pragma unroll
    for (int r = 0; r < RR; ++r) {
        float dsum = 0.f, nx = 0.f, ny = 0.f;
#pragma unroll
        for (int j = 0; j < 2; ++j) {
            const long ro = (long)(r * 2 + j) * (BB * NN) + row;
            dsum += den[ro * HH + hh];
            const unsigned wv = num[ro * 64 + l];
            nx += __uint_as_float(wv << 16);
            ny += __uint_as_float(wv & 0xffff0000u);
        }
        const float inv = (dsum > 0.f) ? 1.0f / dsum : 0.0f;
        ax = fmaf(nx, inv, ax);
        ay = fmaf(ny, inv, ay);
    }
    const float x0 = hx + ax * (1.0f / RR);
    const float x1 = hy + ay * (1.0f / RR);
    float s = x0 + x1, q = x0 * x0 + x1 * x1;
#pragma unroll
    for (int m = 1; m < 64; m <<= 1) {
        s += __shfl_xor(s, m);
        q += __shfl_xor(q, m);
    }
    const float mu  = s * (1.0f / DD);
    const float var = q * (1.0f / DD) - mu * mu;
    const float inv = rsqrtf(var + LN_EPS);
    out[row * DD + c_lo] = (x0 - mu) * inv * gamma[c_lo] + beta[c_lo];
    out[row * DD + c_hi] = (x1 - mu) * inv * gamma[c_hi] + beta[c_hi];
}

// ---------------------------------------------------------------------------
extern "C" void kernel_launch(void* const* d_in, const int* in_sizes, int n_in,
                              void* d_out, int out_size, void* d_ws, size_t ws_size,
                              hipStream_t stream)
{
    const float* H      = (const float*)d_in[0];
    const int*   A      = (const int*)d_in[1];
    const float* W      = (const float*)d_in[2];
    const float* a_src  = (const float*)d_in[3];
    const float* a_dst  = (const float*)d_in[4];
    const float* gamma  = (const float*)d_in[5];
    const float* beta   = (const float*)d_in[6];
    float* out = (float*)d_out;

    // workspace carve (~13.4 MB)
    char* ws = (char*)d_ws;
    unsigned* num = (unsigned*)ws;               ws += (size_t)RR * 2 * BB * NN * 64 * 4;
    float* den = (float*)ws;                     ws += (size_t)RR * 2 * BB * NN * HH * 4;
    float* es  = (float*)ws;                     ws += (size_t)RR * BB * HH * NN * 4;
    float* ed  = (float*)ws;                     ws += (size_t)RR * BB * HH * NN * 4;
    __hip_bfloat16* whT = (__hip_bfloat16*)ws;   ws += (size_t)RR * BB * HH * HD * NN * 2;
    unsigned* bmask = (unsigned*)ws;             ws += (size_t)RR * BB * NN * (NN / 32) * 4;

    prep_kernel<<<768 + 384, 256, 0, stream>>>(
        H, A, W, a_src, a_dst, es, ed, whT, bmask);
    gat_attn_kernel<<<RR * BB * 128 * 2, 256, 0, stream>>>(bmask, es, ed, whT, num, den);
    finalize_kernel<<<BB * NN / 4, 256, 0, stream>>>(H, num, den, gamma, beta, out);
}